// Round 2
// baseline (1126.650 us; speedup 1.0000x reference)
//
#include <hip/hip_runtime.h>
#include <hip/hip_bf16.h>
#include <math.h>

#define BB 16
#define CC 512
#define HWN 4096
#define KK 4
#define DD 32
#define KD 128

// workspace layout (float offsets)
#define WS_Y     0         // [B*C]      = 8192
#define WS_WGT   8192      // [B*K]      = 64
#define WS_BIAS2 8256      // [B*C]      = 8192
#define WS_W1T   16448     // [C][KD]    = 65536  (w1t[c][kd] = w1[kd][c])
#define WS_W2T   81984     // [C][KD]    = 65536  (w2t[c][kd] = w2[k][c][d])

// ---------------- kernel 1: y[b,c] = mean_{hw} x[b,c,hw] ----------------
__global__ __launch_bounds__(256) void mean_kernel(const float* __restrict__ x,
                                                   float* __restrict__ y) {
    int wave = threadIdx.x >> 6;
    int lane = threadIdx.x & 63;
    int row  = blockIdx.x * 4 + wave;            // row in [0, B*C)
    const float4* xr = (const float4*)(x + (size_t)row * HWN);
    float s = 0.f;
    #pragma unroll
    for (int i = 0; i < 16; i++) {
        float4 v = xr[i * 64 + lane];
        s += (v.x + v.y) + (v.z + v.w);
    }
    #pragma unroll
    for (int off = 32; off > 0; off >>= 1)
        s += __shfl_down(s, off, 64);
    if (lane == 0) y[row] = s * (1.0f / HWN);
}

// ---------------- kernel 2: routing softmax -> wgt[b,k] ----------------
__global__ __launch_bounds__(64) void route_kernel(const float* __restrict__ y,
                                                   const float* __restrict__ fc_w,
                                                   const float* __restrict__ fc_b,
                                                   float* __restrict__ wgt) {
    __shared__ float logits[BB][KK];
    int t = threadIdx.x;                 // 64 threads, one per (b,k)
    int b = t >> 2, k = t & 3;
    const float4* y4 = (const float4*)(y + b * CC);
    const float4* f4 = (const float4*)(fc_w + k * CC);
    float s = fc_b[k];
    for (int i = 0; i < CC / 4; i++) {
        float4 a = y4[i], w = f4[i];
        s += a.x * w.x + a.y * w.y + a.z * w.z + a.w * w.w;
    }
    logits[b][k] = s;
    __syncthreads();
    if (k == 0) {
        float m = logits[b][0];
        #pragma unroll
        for (int j = 1; j < KK; j++) m = fmaxf(m, logits[b][j]);
        float e[KK], sum = 0.f;
        #pragma unroll
        for (int j = 0; j < KK; j++) { e[j] = __expf(logits[b][j] - m); sum += e[j]; }
        float inv = 1.f / sum;
        #pragma unroll
        for (int j = 0; j < KK; j++) wgt[b * KK + j] = e[j] * inv;
    }
}

// -------- kernel 3: transposes + bias2[b,c] = sum_k wgt[b,k]*b2[k,c] --------
__global__ __launch_bounds__(256) void prep_kernel(const float* __restrict__ w1,
                                                   const float* __restrict__ w2,
                                                   const float* __restrict__ b2,
                                                   const float* __restrict__ wgt,
                                                   float* __restrict__ w1t,
                                                   float* __restrict__ w2t,
                                                   float* __restrict__ bias2) {
    int tid = blockIdx.x * 256 + threadIdx.x;
    int n   = gridDim.x * 256;
    for (int i = tid; i < CC * KD; i += n) {
        int c = i >> 7, kd = i & 127;
        w1t[i] = w1[kd * CC + c];                       // w1 is [KD][C]
    }
    for (int i = tid; i < CC * KD; i += n) {
        int c = i >> 7, kd = i & 127;
        int k = kd >> 5, d = kd & 31;
        w2t[i] = w2[(k * CC + c) * DD + d];             // w2 is [K][C][D]
    }
    for (int i = tid; i < BB * CC; i += n) {
        int b = i >> 9, c = i & 511;
        float s = 0.f;
        #pragma unroll
        for (int k = 0; k < KK; k++) s += wgt[b * KK + k] * b2[k * CC + c];
        bias2[i] = s;
    }
}

// ---------------- kernel 4: fused MLP + sigmoid + multiply ----------------
// 1 thread = 1 pixel. grid = (HW/256, B), block = 256.
__global__ __launch_bounds__(256) void main_kernel(const float* __restrict__ x,
                                                   const float* __restrict__ w1t,
                                                   const float* __restrict__ b1,
                                                   const float* __restrict__ w2t,
                                                   const float* __restrict__ wgt,
                                                   const float* __restrict__ bias2,
                                                   float* __restrict__ out) {
    int b  = blockIdx.y;
    int hw = blockIdx.x * 256 + threadIdx.x;
    const float* xb = x + (size_t)b * CC * HWN + hw;

    float acc[KD];
    #pragma unroll
    for (int i = 0; i < KD; i++) acc[i] = 0.f;

    // phase 1: hid = W1 @ x_col   (w1t reads are block-uniform -> s_load)
    #pragma unroll 2
    for (int c = 0; c < CC; c++) {
        float xv = xb[(size_t)c * HWN];
        const float* w1c = w1t + c * KD;
        #pragma unroll
        for (int kd = 0; kd < KD; kd++)
            acc[kd] = fmaf(w1c[kd], xv, acc[kd]);
    }

    // relu + fold routing weight
    float wk[KK];
    #pragma unroll
    for (int k = 0; k < KK; k++) wk[k] = wgt[b * KK + k];
    #pragma unroll
    for (int kd = 0; kd < KD; kd++) {
        float h = fmaxf(acc[kd] + b1[kd], 0.f);
        acc[kd] = h * wk[kd >> 5];
    }

    // phase 2: out_c = w2t[c,:] . hid + bias2; gate; multiply; store
    float* ob = out + (size_t)b * CC * HWN + hw;
    const float* bb = bias2 + b * CC;
    #pragma unroll 2
    for (int c = 0; c < CC; c++) {
        const float* w2c = w2t + c * KD;
        float s0 = 0.f, s1 = 0.f, s2 = 0.f, s3 = 0.f;
        #pragma unroll
        for (int kd = 0; kd < KD; kd += 4) {
            s0 = fmaf(w2c[kd + 0], acc[kd + 0], s0);
            s1 = fmaf(w2c[kd + 1], acc[kd + 1], s1);
            s2 = fmaf(w2c[kd + 2], acc[kd + 2], s2);
            s3 = fmaf(w2c[kd + 3], acc[kd + 3], s3);
        }
        float s = bb[c] + ((s0 + s1) + (s2 + s3));
        float attn = __builtin_amdgcn_rcpf(1.f + __expf(-s));
        ob[(size_t)c * HWN] = xb[(size_t)c * HWN] * attn;
    }
}

extern "C" void kernel_launch(void* const* d_in, const int* in_sizes, int n_in,
                              void* d_out, int out_size, void* d_ws, size_t ws_size,
                              hipStream_t stream) {
    const float* x    = (const float*)d_in[0];
    const float* fc_w = (const float*)d_in[1];
    const float* fc_b = (const float*)d_in[2];
    const float* w1   = (const float*)d_in[3];
    const float* b1   = (const float*)d_in[4];
    const float* w2   = (const float*)d_in[5];
    const float* b2   = (const float*)d_in[6];
    float* out = (float*)d_out;
    float* ws  = (float*)d_ws;

    float* y     = ws + WS_Y;
    float* wgt   = ws + WS_WGT;
    float* bias2 = ws + WS_BIAS2;
    float* w1t   = ws + WS_W1T;
    float* w2t   = ws + WS_W2T;

    mean_kernel <<<dim3(BB * CC / 4), dim3(256), 0, stream>>>(x, y);
    route_kernel<<<dim3(1),           dim3(64),  0, stream>>>(y, fc_w, fc_b, wgt);
    prep_kernel <<<dim3(128),         dim3(256), 0, stream>>>(w1, w2, b2, wgt, w1t, w2t, bias2);
    main_kernel <<<dim3(HWN / 256, BB), dim3(256), 0, stream>>>(x, w1t, b1, w2t, wgt, bias2, out);
}

// Round 3
// 334.404 us; speedup vs baseline: 3.3691x; 3.3691x over previous
//
#include <hip/hip_runtime.h>
#include <hip/hip_bf16.h>
#include <math.h>

#define BB 16
#define CC 512
#define HWN 4096
#define KK 4
#define DD 32
#define KD 128
#define NPIX 64

typedef __attribute__((ext_vector_type(8))) short short8;
typedef __attribute__((ext_vector_type(4))) float f32x4;

// ws float offsets
#define WS_Y     0         // [B*C]            8192 f
#define WS_WGT   8192      // [B*K]            64 f
#define WS_BIAS2 8256      // [B*C]            8192 f
#define WS_W1B   16448     // 65536 ushort  = 32768 f  (frag-packed bf16 W1)
#define WS_W2B   49216     // 65536 ushort  = 32768 f  (frag-packed bf16 W2t)

__device__ inline unsigned short f2bf(float f) {
    unsigned u = __builtin_bit_cast(unsigned, f);
    unsigned r = (u + 0x7FFFu + ((u >> 16) & 1u)) >> 16;
    return (unsigned short)r;
}

// ---------------- kernel 1: y[b,c] = mean_{hw} x[b,c,hw] ----------------
__global__ __launch_bounds__(256) void mean_kernel(const float* __restrict__ x,
                                                   float* __restrict__ y) {
    int wave = threadIdx.x >> 6;
    int lane = threadIdx.x & 63;
    int row  = blockIdx.x * 4 + wave;
    const float4* xr = (const float4*)(x + (size_t)row * HWN);
    float s = 0.f;
    #pragma unroll
    for (int i = 0; i < 16; i++) {
        float4 v = xr[i * 64 + lane];
        s += (v.x + v.y) + (v.z + v.w);
    }
    #pragma unroll
    for (int off = 32; off > 0; off >>= 1)
        s += __shfl_down(s, off, 64);
    if (lane == 0) y[row] = s * (1.0f / HWN);
}

// ---------------- kernel 2: routing softmax -> wgt[b,k] ----------------
__global__ __launch_bounds__(64) void route_kernel(const float* __restrict__ y,
                                                   const float* __restrict__ fc_w,
                                                   const float* __restrict__ fc_b,
                                                   float* __restrict__ wgt) {
    __shared__ float logits[BB][KK];
    int t = threadIdx.x;
    int b = t >> 2, k = t & 3;
    const float4* y4 = (const float4*)(y + b * CC);
    const float4* f4 = (const float4*)(fc_w + k * CC);
    float s = fc_b[k];
    for (int i = 0; i < CC / 4; i++) {
        float4 a = y4[i], w = f4[i];
        s += a.x * w.x + a.y * w.y + a.z * w.z + a.w * w.w;
    }
    logits[b][k] = s;
    __syncthreads();
    if (k == 0) {
        float m = logits[b][0];
        #pragma unroll
        for (int j = 1; j < KK; j++) m = fmaxf(m, logits[b][j]);
        float e[KK], sum = 0.f;
        #pragma unroll
        for (int j = 0; j < KK; j++) { e[j] = __expf(logits[b][j] - m); sum += e[j]; }
        float inv = 1.f / sum;
        #pragma unroll
        for (int j = 0; j < KK; j++) wgt[b * KK + j] = e[j] * inv;
    }
}

// ---- kernel 3: pack W1/W2t into MFMA-fragment-ordered bf16; bias2 ----
// w1b element (frag f = ks*8+m, lane l, i) = W1[m*16 + l%16][ks*32 + (l/16)*8 + i]
// w2b element (frag f = mc*4+kk, lane l, i) = W2t[mc*16 + l%16][kk*32 + (l/16)*8 + i]
//   where W2t[c][kd] = w2[kd/32][c][kd%32]
__global__ __launch_bounds__(256) void prep_kernel(const float* __restrict__ w1,
                                                   const float* __restrict__ w2,
                                                   const float* __restrict__ b2,
                                                   const float* __restrict__ wgt,
                                                   unsigned short* __restrict__ w1b,
                                                   unsigned short* __restrict__ w2b,
                                                   float* __restrict__ bias2) {
    int tid = blockIdx.x * 256 + threadIdx.x;
    int n   = gridDim.x * 256;
    for (int idx = tid; idx < CC * KD; idx += n) {
        int f = idx >> 9, rem = idx & 511;
        int l = rem >> 3, i = rem & 7;
        int ks = f >> 3, m = f & 7;
        int kd = m * 16 + (l & 15);
        int c  = ks * 32 + (l >> 4) * 8 + i;
        w1b[idx] = f2bf(w1[kd * CC + c]);          // w1 is [KD][C]
    }
    for (int idx = tid; idx < CC * KD; idx += n) {
        int f = idx >> 9, rem = idx & 511;
        int l = rem >> 3, i = rem & 7;
        int mc = f >> 2, kk = f & 3;
        int c = mc * 16 + (l & 15);
        int d = (l >> 4) * 8 + i;                  // kd = kk*32 + d, expert = kk
        w2b[idx] = f2bf(w2[(kk * CC + c) * DD + d]); // w2 is [K][C][D]
    }
    for (int idx = tid; idx < BB * CC; idx += n) {
        int bb = idx >> 9, c = idx & 511;
        float s = 0.f;
        #pragma unroll
        for (int k = 0; k < KK; k++) s += wgt[bb * KK + k] * b2[k * CC + c];
        bias2[idx] = s;
    }
}

// ---------------- kernel 4: fused MFMA MLP + sigmoid + multiply ----------------
// grid (HW/64, B), block 256 = 4 waves. Wave w: GEMM1 for pix [w*16,w*16+16),
// all 128 kd; GEMM2 for c [w*128,(w+1)*128), all 64 pix.
__global__ __launch_bounds__(256, 2) void main_kernel(const float* __restrict__ x,
                                                      const unsigned short* __restrict__ w1b,
                                                      const float* __restrict__ b1,
                                                      const unsigned short* __restrict__ w2b,
                                                      const float* __restrict__ wgt,
                                                      const float* __restrict__ bias2,
                                                      float* __restrict__ out) {
    __shared__ unsigned short hid_lds[NPIX * KD];   // [pix][kd], XOR-swizzled

    const int b       = blockIdx.y;
    const int pixbase = blockIdx.x * NPIX;
    const int tid = threadIdx.x;
    const int wv  = tid >> 6;
    const int l   = tid & 63;
    const int l15 = l & 15, lg = l >> 4;

    const float* xb = x + (size_t)b * CC * HWN;
    const short8* w1f = (const short8*)w1b;
    const short8* w2f = (const short8*)w2b;

    // ================= GEMM1: hid = relu(W1 @ x + b1) * wgt =================
    f32x4 acc1[8];
    #pragma unroll
    for (int m = 0; m < 8; m++) acc1[m] = (f32x4)0.f;

    const int mypix = pixbase + wv * 16 + l15;
    #pragma unroll 2
    for (int ks = 0; ks < 16; ks++) {
        const float* xcol = xb + (size_t)(ks * 32 + lg * 8) * HWN + mypix;
        short8 bf;
        #pragma unroll
        for (int i = 0; i < 8; i++) bf[i] = (short)f2bf(xcol[(size_t)i * HWN]);
        #pragma unroll
        for (int m = 0; m < 8; m++) {
            short8 af = w1f[(ks * 8 + m) * 64 + l];
            acc1[m] = __builtin_amdgcn_mfma_f32_16x16x32_bf16(af, bf, acc1[m], 0, 0, 0);
        }
    }

    // relu + bias + routing-weight fold; write hid to LDS (bf16)
    {
        const int row = wv * 16 + l15;
        #pragma unroll
        for (int m = 0; m < 8; m++) {
            f32x4 bv = *(const f32x4*)(b1 + m * 16 + lg * 4);
            float w = wgt[b * KK + (m >> 1)];
            unsigned short h[4];
            #pragma unroll
            for (int r = 0; r < 4; r++) {
                float t = fmaxf(acc1[m][r] + bv[r], 0.f) * w;
                h[r] = f2bf(t);
            }
            unsigned lo = (unsigned)h[0] | ((unsigned)h[1] << 16);
            unsigned hi = (unsigned)h[2] | ((unsigned)h[3] << 16);
            int byteoff = row * 256 + (m * 16 + lg * 4) * 2;
            byteoff ^= (row & 7) << 4;
            uint2 v; v.x = lo; v.y = hi;
            *(uint2*)((char*)hid_lds + byteoff) = v;
        }
    }
    __syncthreads();

    // ================= GEMM2: out = sigmoid(W2t @ hid + bias2) * x =================
    short8 breg[4][4];   // [kk][nb]
    #pragma unroll
    for (int kk = 0; kk < 4; kk++) {
        #pragma unroll
        for (int nb = 0; nb < 4; nb++) {
            int row = nb * 16 + l15;
            int byteoff = row * 256 + (kk * 32 + lg * 8) * 2;
            byteoff ^= (row & 7) << 4;
            breg[kk][nb] = *(const short8*)((const char*)hid_lds + byteoff);
        }
    }

    const int wcbase = wv * 128;
    #pragma unroll 2
    for (int mblk = 0; mblk < 8; mblk++) {
        f32x4 acc[4];
        #pragma unroll
        for (int nb = 0; nb < 4; nb++) acc[nb] = (f32x4)0.f;
        #pragma unroll
        for (int kk = 0; kk < 4; kk++) {
            short8 af = w2f[((wv * 8 + mblk) * 4 + kk) * 64 + l];
            #pragma unroll
            for (int nb = 0; nb < 4; nb++)
                acc[nb] = __builtin_amdgcn_mfma_f32_16x16x32_bf16(af, breg[kk][nb], acc[nb], 0, 0, 0);
        }
        const int cb = wcbase + mblk * 16 + lg * 4;
        f32x4 b2v = *(const f32x4*)(bias2 + b * CC + cb);
        #pragma unroll
        for (int nb = 0; nb < 4; nb++) {
            int pix = pixbase + nb * 16 + l15;
            #pragma unroll
            for (int r = 0; r < 4; r++) {
                size_t off = ((size_t)b * CC + cb + r) * HWN + pix;
                float s = acc[nb][r] + b2v[r];
                float attn = __builtin_amdgcn_rcpf(1.f + __expf(-s));
                out[off] = x[off] * attn;
            }
        }
    }
}

extern "C" void kernel_launch(void* const* d_in, const int* in_sizes, int n_in,
                              void* d_out, int out_size, void* d_ws, size_t ws_size,
                              hipStream_t stream) {
    const float* x    = (const float*)d_in[0];
    const float* fc_w = (const float*)d_in[1];
    const float* fc_b = (const float*)d_in[2];
    const float* w1   = (const float*)d_in[3];
    const float* b1   = (const float*)d_in[4];
    const float* w2   = (const float*)d_in[5];
    const float* b2   = (const float*)d_in[6];
    float* out = (float*)d_out;
    float* ws  = (float*)d_ws;

    float* y     = ws + WS_Y;
    float* wgt   = ws + WS_WGT;
    float* bias2 = ws + WS_BIAS2;
    unsigned short* w1b = (unsigned short*)(ws + WS_W1B);
    unsigned short* w2b = (unsigned short*)(ws + WS_W2B);

    mean_kernel <<<dim3(BB * CC / 4), dim3(256), 0, stream>>>(x, y);
    route_kernel<<<dim3(1),           dim3(64),  0, stream>>>(y, fc_w, fc_b, wgt);
    prep_kernel <<<dim3(128),         dim3(256), 0, stream>>>(w1, w2, b2, wgt, w1b, w2b, bias2);
    main_kernel <<<dim3(HWN / NPIX, BB), dim3(256), 0, stream>>>(x, w1b, b1, w2b, wgt, bias2, out);
}

// Round 5
// 307.609 us; speedup vs baseline: 3.6626x; 1.0871x over previous
//
#include <hip/hip_runtime.h>
#include <hip/hip_bf16.h>
#include <math.h>

#define BB 16
#define CC 512
#define HWN 4096
#define KK 4
#define DD 32
#define KD 128
#define NPIX 64

typedef __attribute__((ext_vector_type(8))) short short8;
typedef __attribute__((ext_vector_type(4))) float f32x4;

// ws float offsets
#define WS_Y     0         // [B*C]            8192 f
#define WS_WGT   8192      // [B*K]            64 f
#define WS_BIAS2 8256      // [B*C]            8192 f
#define WS_W1B   16448     // 65536 ushort  = 32768 f  (frag-packed bf16 W1)
#define WS_W2B   49216     // 65536 ushort  = 32768 f  (frag-packed bf16 W2t)

__device__ inline unsigned short f2bf(float f) {
    unsigned u = __builtin_bit_cast(unsigned, f);
    unsigned r = (u + 0x7FFFu + ((u >> 16) & 1u)) >> 16;
    return (unsigned short)r;
}

// ---------------- kernel 1: y[b,c] = mean_{hw} x[b,c,hw] ----------------
__global__ __launch_bounds__(256) void mean_kernel(const float* __restrict__ x,
                                                   float* __restrict__ y) {
    int wave = threadIdx.x >> 6;
    int lane = threadIdx.x & 63;
    int row  = blockIdx.x * 4 + wave;
    const float4* xr = (const float4*)(x + (size_t)row * HWN);
    float s = 0.f;
    #pragma unroll
    for (int i = 0; i < 16; i++) {
        float4 v = xr[i * 64 + lane];
        s += (v.x + v.y) + (v.z + v.w);
    }
    #pragma unroll
    for (int off = 32; off > 0; off >>= 1)
        s += __shfl_down(s, off, 64);
    if (lane == 0) y[row] = s * (1.0f / HWN);
}

// ---------------- kernel 2: routing softmax -> wgt[b,k] ----------------
__global__ __launch_bounds__(64) void route_kernel(const float* __restrict__ y,
                                                   const float* __restrict__ fc_w,
                                                   const float* __restrict__ fc_b,
                                                   float* __restrict__ wgt) {
    __shared__ float logits[BB][KK];
    int t = threadIdx.x;
    int b = t >> 2, k = t & 3;
    const float4* y4 = (const float4*)(y + b * CC);
    const float4* f4 = (const float4*)(fc_w + k * CC);
    float s = fc_b[k];
    for (int i = 0; i < CC / 4; i++) {
        float4 a = y4[i], w = f4[i];
        s += a.x * w.x + a.y * w.y + a.z * w.z + a.w * w.w;
    }
    logits[b][k] = s;
    __syncthreads();
    if (k == 0) {
        float m = logits[b][0];
        #pragma unroll
        for (int j = 1; j < KK; j++) m = fmaxf(m, logits[b][j]);
        float e[KK], sum = 0.f;
        #pragma unroll
        for (int j = 0; j < KK; j++) { e[j] = __expf(logits[b][j] - m); sum += e[j]; }
        float inv = 1.f / sum;
        #pragma unroll
        for (int j = 0; j < KK; j++) wgt[b * KK + j] = e[j] * inv;
    }
}

// ---- kernel 3: pack W1/W2t into MFMA-fragment-ordered bf16; bias2 ----
__global__ __launch_bounds__(256) void prep_kernel(const float* __restrict__ w1,
                                                   const float* __restrict__ w2,
                                                   const float* __restrict__ b2,
                                                   const float* __restrict__ wgt,
                                                   unsigned short* __restrict__ w1b,
                                                   unsigned short* __restrict__ w2b,
                                                   float* __restrict__ bias2) {
    int tid = blockIdx.x * 256 + threadIdx.x;
    int n   = gridDim.x * 256;
    for (int idx = tid; idx < CC * KD; idx += n) {
        int f = idx >> 9, rem = idx & 511;
        int l = rem >> 3, i = rem & 7;
        int ks = f >> 3, m = f & 7;
        int kd = m * 16 + (l & 15);
        int c  = ks * 32 + (l >> 4) * 8 + i;
        w1b[idx] = f2bf(w1[kd * CC + c]);            // w1 is [KD][C]
    }
    for (int idx = tid; idx < CC * KD; idx += n) {
        int f = idx >> 9, rem = idx & 511;
        int l = rem >> 3, i = rem & 7;
        int mc = f >> 2, kk = f & 3;
        int c = mc * 16 + (l & 15);
        int d = (l >> 4) * 8 + i;
        w2b[idx] = f2bf(w2[(kk * CC + c) * DD + d]); // w2 is [K][C][D]
    }
    for (int idx = tid; idx < BB * CC; idx += n) {
        int bb = idx >> 9, c = idx & 511;
        float s = 0.f;
        #pragma unroll
        for (int k = 0; k < KK; k++) s += wgt[bb * KK + k] * b2[k * CC + c];
        bias2[idx] = s;
    }
}

// ---------------- kernel 4: fused MFMA MLP, split-K, 8 waves ----------------
// grid (HW/64, B), block 512 = 8 waves. wave wv: pg = wv&3 (16-pixel group),
// kh = wv>>2 (C-half). GEMM1: partial over C-half; upper waves publish fp32
// partials to LDS; lower waves reduce + relu + wgt -> bf16 hid (overlapping
// LDS region, per-pg disjoint). GEMM2: 64 output channels per wave.
__global__ __launch_bounds__(512, 4) void main_kernel(const float* __restrict__ x,
                                                      const unsigned short* __restrict__ w1b,
                                                      const float* __restrict__ b1,
                                                      const unsigned short* __restrict__ w2b,
                                                      const float* __restrict__ wgt,
                                                      const float* __restrict__ bias2,
                                                      float* __restrict__ out) {
    __shared__ char lds[4 * 8192];   // [pg][8 KB]: fp32 partials, hid bf16 reuses first 4 KB

    const int b       = blockIdx.y;
    const int pixbase = blockIdx.x * NPIX;
    const int tid = threadIdx.x;
    const int wv  = tid >> 6;
    const int l   = tid & 63;
    const int l15 = l & 15, lg = l >> 4;
    const int pg  = wv & 3;
    const int kh  = wv >> 2;

    const float* xb = x + (size_t)b * CC * HWN;
    const short8* w1f = (const short8*)w1b;
    const short8* w2f = (const short8*)w2b;

    // ===== GEMM1 partial: ks in [kh*8, kh*8+8) =====
    f32x4 acc1[8];
    #pragma unroll
    for (int m = 0; m < 8; m++) acc1[m] = (f32x4)0.f;

    const int mypix = pixbase + pg * 16 + l15;
    const float* xc = xb + (size_t)(kh * 256 + lg * 8) * HWN + mypix;

    float xv[8];
    #pragma unroll
    for (int i = 0; i < 8; i++) xv[i] = xc[(size_t)i * HWN];

    #pragma unroll
    for (int ks8 = 0; ks8 < 8; ks8++) {
        short8 bf;
        #pragma unroll
        for (int i = 0; i < 8; i++) bf[i] = (short)f2bf(xv[i]);
        if (ks8 < 7) {
            const float* xn = xc + (size_t)((ks8 + 1) * 32) * HWN;
            #pragma unroll
            for (int i = 0; i < 8; i++) xv[i] = xn[(size_t)i * HWN];
        }
        const int ks = kh * 8 + ks8;
        #pragma unroll
        for (int m = 0; m < 8; m++) {
            short8 af = w1f[(ks * 8 + m) * 64 + l];
            acc1[m] = __builtin_amdgcn_mfma_f32_16x16x32_bf16(af, bf, acc1[m], 0, 0, 0);
        }
    }

    // ===== upper waves publish fp32 partials (contiguous 1 KB/wave) =====
    if (kh == 1) {
        char* base = lds + pg * 8192 + lg * 256 + l15 * 16;
        #pragma unroll
        for (int m = 0; m < 8; m++)
            *(f32x4*)(base + m * 1024) = acc1[m];
    }
    __syncthreads();

    // ===== lower waves: reduce + relu + bias + wgt -> bf16 hid =====
    // chunked by 4 m so hid writes (first 4 KB of pg block) never clobber
    // not-yet-read partials (m=4..7 live in second 4 KB).
    if (kh == 0) {
        const char* pbase = lds + pg * 8192 + lg * 256 + l15 * 16;
        #pragma unroll
        for (int half = 0; half < 2; half++) {
            f32x4 pp[4];
            #pragma unroll
            for (int m4 = 0; m4 < 4; m4++)
                pp[m4] = *(const f32x4*)(pbase + (half * 4 + m4) * 1024);
            #pragma unroll
            for (int m4 = 0; m4 < 4; m4++) {
                const int m = half * 4 + m4;
                f32x4 bv = *(const f32x4*)(b1 + m * 16 + lg * 4);
                float wk = wgt[b * KK + (m >> 1)];
                f32x4 s = acc1[m] + pp[m4];
                unsigned short h[4];
                #pragma unroll
                for (int r = 0; r < 4; r++) {
                    float t = fmaxf(s[r] + bv[r], 0.f) * wk;
                    h[r] = f2bf(t);
                }
                unsigned lo = (unsigned)h[0] | ((unsigned)h[1] << 16);
                unsigned hi = (unsigned)h[2] | ((unsigned)h[3] << 16);
                int byteoff = pg * 8192 + l15 * 256 + (m * 16 + lg * 4) * 2;
                byteoff ^= (l15 & 7) << 4;
                uint2 v; v.x = lo; v.y = hi;
                *(uint2*)(lds + byteoff) = v;
            }
        }
    }
    __syncthreads();

    // ===== GEMM2: 64 channels per wave, sigmoid gate, multiply, store =====
    const float* bb2 = bias2 + b * CC;
    #pragma unroll
    for (int mblk = 0; mblk < 4; mblk++) {
        f32x4 acc[4];
        #pragma unroll
        for (int nb = 0; nb < 4; nb++) acc[nb] = (f32x4)0.f;
        #pragma unroll
        for (int kk = 0; kk < 4; kk++) {
            short8 af = w2f[((wv * 4 + mblk) * 4 + kk) * 64 + l];
            #pragma unroll
            for (int nb = 0; nb < 4; nb++) {
                int byteoff = nb * 8192 + l15 * 256 + kk * 64 + lg * 16;
                byteoff ^= (l15 & 7) << 4;
                short8 bf = *(const short8*)(lds + byteoff);
                acc[nb] = __builtin_amdgcn_mfma_f32_16x16x32_bf16(af, bf, acc[nb], 0, 0, 0);
            }
        }
        const int cb = wv * 64 + mblk * 16 + lg * 4;
        f32x4 b2v = *(const f32x4*)(bb2 + cb);
        #pragma unroll
        for (int nb = 0; nb < 4; nb++) {
            int pix = pixbase + nb * 16 + l15;
            #pragma unroll
            for (int r = 0; r < 4; r++) {
                size_t off = ((size_t)b * CC + cb + r) * HWN + pix;
                float s = acc[nb][r] + b2v[r];
                float attn = __builtin_amdgcn_rcpf(1.f + __expf(-s));
                __builtin_nontemporal_store(x[off] * attn, &out[off]);
            }
        }
    }
}

extern "C" void kernel_launch(void* const* d_in, const int* in_sizes, int n_in,
                              void* d_out, int out_size, void* d_ws, size_t ws_size,
                              hipStream_t stream) {
    const float* x    = (const float*)d_in[0];
    const float* fc_w = (const float*)d_in[1];
    const float* fc_b = (const float*)d_in[2];
    const float* w1   = (const float*)d_in[3];
    const float* b1   = (const float*)d_in[4];
    const float* w2   = (const float*)d_in[5];
    const float* b2   = (const float*)d_in[6];
    float* out = (float*)d_out;
    float* ws  = (float*)d_ws;

    float* y     = ws + WS_Y;
    float* wgt   = ws + WS_WGT;
    float* bias2 = ws + WS_BIAS2;
    unsigned short* w1b = (unsigned short*)(ws + WS_W1B);
    unsigned short* w2b = (unsigned short*)(ws + WS_W2B);

    mean_kernel <<<dim3(BB * CC / 4), dim3(256), 0, stream>>>(x, y);
    route_kernel<<<dim3(1),           dim3(64),  0, stream>>>(y, fc_w, fc_b, wgt);
    prep_kernel <<<dim3(128),         dim3(256), 0, stream>>>(w1, w2, b2, wgt, w1b, w2b, bias2);
    main_kernel <<<dim3(HWN / NPIX, BB), dim3(512), 0, stream>>>(x, w1b, b1, w2b, wgt, bias2, out);
}